// Round 2
// baseline (180.792 us; speedup 1.0000x reference)
//
#include <hip/hip_runtime.h>

// ReconstructPatchImage: out[b,c,y,x] = sum of 8 permuted gathers of [B,HW,C] inputs.
// B=64, HW=196 (H=W=14), C=1024, all float32.
//
// Per-input flat (per-batch) source index for output (c, q=y*14+x):
//   in0 (l2r):  q*1024 + c
//   in1 (r2l):  (195-q)*1024 + c
//   in2 (t2b):  x*14336 + c*14 + y              (channel-mixing col-major view)
//   in3 (b2t):  (195 - x*14 - hi)*1024 + lo,  t=c*14+y, hi=t>>10, lo=t&1023
//   in4 (tl-br): p5[q]*1024 + c
//   in5 (br-tl): p6[q]*1024 + c
//   in6 (tr-bl): p7[q]*1024 + c
//   in7 (bl-tr): p7[195-q]*1024 + c
//
// R1: no LDS staging, no mid-kernel barriers. 7-wave block; wave w owns
// q = w*28..w*28+27 (y in {2w,2w+1}, all x) so in2/in3 become float2 loads.
// Perm inputs: wave-uniform row + lane-contiguous dword loads (coalesced).
// Single LDS transpose at the end for coalesced output stores.

#define N_HW 196
#define N_C  1024

struct Luts { unsigned short p5[196], p6[196], p7[196]; };

constexpr Luts make_luts() {
    Luts L{};
    int k = 0;
    for (int s = 0; s < 27; ++s) {
        int y0 = (s - 13 > 0) ? s - 13 : 0;
        int y1 = (s < 13) ? s : 13;
        for (int y = y0; y <= y1; ++y) {
            int x = s - y;
            L.p5[y * 14 + x] = (unsigned short)k;
            L.p7[y * 14 + (13 - x)] = (unsigned short)k;
            ++k;
        }
    }
    int k2 = 0;
    for (int s = 0; s < 27; ++s) {
        int x1 = (s < 13) ? s : 13;
        int x0 = (s - 13 > 0) ? s - 13 : 0;
        for (int x = x1; x >= x0; --x) {
            int y = s - x;
            L.p6[y * 14 + x] = (unsigned short)(195 - k2);
            ++k2;
        }
    }
    return L;
}

__constant__ Luts d_luts = make_luts();

__global__ __launch_bounds__(448) void recon_kernel(
    const float* __restrict__ in0, const float* __restrict__ in1,
    const float* __restrict__ in2, const float* __restrict__ in3,
    const float* __restrict__ in4, const float* __restrict__ in5,
    const float* __restrict__ in6, const float* __restrict__ in7,
    float* __restrict__ out)
{
    __shared__ __align__(16) float lds[196 * 65];     // 50960 B
    const int tid  = threadIdx.x;
    const int lane = tid & 63;
    const int wv   = tid >> 6;
    const int w0   = __builtin_amdgcn_readfirstlane(wv);   // scalar wave id 0..6
    const int c0   = blockIdx.x * 64;                       // channel tile base
    const int b    = blockIdx.y;
    const size_t boff = (size_t)b * (N_HW * N_C);

    float acc[28];

    // lane-channel bases (perm inputs: wave-uniform row, lane-contiguous col)
    const float* g0 = in0 + boff + c0 + lane;
    const float* g1 = in1 + boff + c0 + lane;
    const float* g4 = in4 + boff + c0 + lane;
    const float* g5 = in5 + boff + c0 + lane;
    const float* g6 = in6 + boff + c0 + lane;
    const float* g7 = in7 + boff + c0 + lane;

    // in0 initializes acc
    #pragma unroll
    for (int k = 0; k < 28; ++k) {
        int q = w0 * 28 + k;
        acc[k] = g0[q * N_C];
    }
    #pragma unroll
    for (int k = 0; k < 28; ++k) {
        int q = w0 * 28 + k;
        acc[k] += g1[(195 - q) * N_C];
    }

    // in2: col-major forward. Per x, one float2 covers y = 2w, 2w+1.
    {
        const float* base2 = in2 + boff + (c0 + lane) * 14 + 2 * w0;
        #pragma unroll
        for (int x = 0; x < 14; ++x) {
            float2 v = *(const float2*)(base2 + x * 14336);
            acc[x]      += v.x;
            acc[14 + x] += v.y;
        }
    }
    // in3: col-major reversed. t = 14c + 2w is even -> float2 never straddles
    // the 1024-float row boundary.
    {
        const float* base3 = in3 + boff;
        int t  = (c0 + lane) * 14 + 2 * w0;
        int hi = t >> 10, lo = t & 1023;
        #pragma unroll
        for (int x = 0; x < 14; ++x) {
            int p = 195 - x * 14 - hi;
            float2 v = *(const float2*)(base3 + p * N_C + lo);
            acc[x]      += v.x;
            acc[14 + x] += v.y;
        }
    }

    #pragma unroll
    for (int k = 0; k < 28; ++k) {
        int q = w0 * 28 + k;
        acc[k] += g4[(int)d_luts.p5[q] * N_C];
    }
    #pragma unroll
    for (int k = 0; k < 28; ++k) {
        int q = w0 * 28 + k;
        acc[k] += g5[(int)d_luts.p6[q] * N_C];
    }
    #pragma unroll
    for (int k = 0; k < 28; ++k) {
        int q = w0 * 28 + k;
        acc[k] += g6[(int)d_luts.p7[q] * N_C];
    }
    #pragma unroll
    for (int k = 0; k < 28; ++k) {
        int q = w0 * 28 + k;
        acc[k] += g7[(int)d_luts.p7[195 - q] * N_C];
    }

    // ---- transpose via LDS (stride 65), coalesced store ----
    #pragma unroll
    for (int k = 0; k < 28; ++k) {
        int q = w0 * 28 + k;
        lds[q * 65 + lane] = acc[k];
    }
    __syncthreads();
    float* ob = out + boff;
    #pragma unroll 4
    for (int i = tid; i < 64 * N_HW; i += 448) {
        int cg = i / N_HW;
        int q  = i - cg * N_HW;
        ob[(c0 + cg) * N_HW + q] = lds[q * 65 + cg];
    }
}

extern "C" void kernel_launch(void* const* d_in, const int* in_sizes, int n_in,
                              void* d_out, int out_size, void* d_ws, size_t ws_size,
                              hipStream_t stream) {
    dim3 grid(16, 64);   // x: channel tile (1024/64), y: batch
    dim3 block(448);     // 7 waves; wave w owns q = w*28 .. w*28+27
    recon_kernel<<<grid, block, 0, stream>>>(
        (const float*)d_in[0], (const float*)d_in[1], (const float*)d_in[2],
        (const float*)d_in[3], (const float*)d_in[4], (const float*)d_in[5],
        (const float*)d_in[6], (const float*)d_in[7], (float*)d_out);
}

// Round 3
// 102.567 us; speedup vs baseline: 1.7627x; 1.7627x over previous
//
#include <hip/hip_runtime.h>

// ReconstructPatchImage: out[b,c,y,x] = sum of 8 permuted gathers of [B,HW,C] inputs.
// B=64, HW=196 (H=W=14), C=1024, all float32.
//
// Per-input flat (per-batch) source index for output (c, q=y*14+x):
//   in0 (l2r):  q*1024 + c
//   in1 (r2l):  (195-q)*1024 + c
//   in2 (t2b):  x*14336 + c*14 + y              (channel-mixing col-major view)
//   in3 (b2t):  (195 - x*14 - hi)*1024 + lo,  t=c*14+y, hi=t>>10, lo=t&1023
//   in4 (tl-br): p5[q]*1024 + c
//   in5 (br-tl): p6[q]*1024 + c
//   in6 (tr-bl): p7[q]*1024 + c
//   in7 (bl-tr): p7[195-q]*1024 + c
//
// R2: global_load_lds staging (deep async queue, no VGPR cost) but with a
// triple-buffered slab pipeline: counted s_waitcnt vmcnt(14) + raw s_barrier,
// never draining the VMEM queue mid-loop (T3/T4). 7 waves -> exactly 7
// gll16 per wave per slab, so per-wave vmcnt arithmetic is uniform.

#define N_HW 196
#define N_C  1024
#define SLAB 12544          // floats per 196x64 slab

struct Luts { unsigned short p5[196], p6[196], p7[196]; };

constexpr Luts make_luts() {
    Luts L{};
    int k = 0;
    for (int s = 0; s < 27; ++s) {
        int y0 = (s - 13 > 0) ? s - 13 : 0;
        int y1 = (s < 13) ? s : 13;
        for (int y = y0; y <= y1; ++y) {
            int x = s - y;
            L.p5[y * 14 + x] = (unsigned short)k;
            L.p7[y * 14 + (13 - x)] = (unsigned short)k;
            ++k;
        }
    }
    int k2 = 0;
    for (int s = 0; s < 27; ++s) {
        int x1 = (s < 13) ? s : 13;
        int x0 = (s - 13 > 0) ? s - 13 : 0;
        for (int x = x1; x >= x0; --x) {
            int y = s - x;
            L.p6[y * 14 + x] = (unsigned short)(195 - k2);
            ++k2;
        }
    }
    return L;
}

__constant__ Luts d_luts = make_luts();

__device__ __forceinline__ void gll16(const float* g, float* l) {
    __builtin_amdgcn_global_load_lds(
        (const __attribute__((address_space(1))) unsigned int*)g,
        (__attribute__((address_space(3))) unsigned int*)l,
        16, 0, 0);
}

#define BAR()    __builtin_amdgcn_s_barrier()
#define VM(n)    asm volatile("s_waitcnt vmcnt(" #n ")" ::: "memory")

__global__ __launch_bounds__(448) void recon_kernel(
    const float* __restrict__ in0, const float* __restrict__ in1,
    const float* __restrict__ in2, const float* __restrict__ in3,
    const float* __restrict__ in4, const float* __restrict__ in5,
    const float* __restrict__ in6, const float* __restrict__ in7,
    float* __restrict__ out)
{
    __shared__ __align__(16) float lds[3 * SLAB];   // 150,528 B; tail transpose reuses front
    const int tid  = threadIdx.x;
    const int lane = tid & 63;
    const int wv   = tid >> 6;
    const int w0   = __builtin_amdgcn_readfirstlane(wv);   // scalar wave id 0..6
    const int c0   = blockIdx.x * 64;
    const int b    = blockIdx.y;
    const size_t boff = (size_t)b * (N_HW * N_C);

    float* bufA = lds;
    float* bufB = lds + SLAB;
    float* bufC = lds + 2 * SLAB;

    // ---- staging: 49 wave-instrs per slab = 7 gll16 per wave ----
    auto stage_perm = [&](const float* gb, float* sb) {
        #pragma unroll
        for (int j = 0; j < 7; ++j) {
            int ch = w0 + 7 * j;                  // 0..48
            int i  = ch * 64 + lane;              // 16B-group index
            int p  = i >> 4;
            int rf = (i & 15) << 2;
            gll16(gb + p * N_C + c0 + rf, sb + ch * 256);
        }
    };
    auto stage_cm_fwd = [&](const float* gb, float* sb) {
        #pragma unroll
        for (int j = 0; j < 7; ++j) {
            int ch = w0 + 7 * j;
            int i  = ch * 64 + lane;
            int x  = i / 224;
            int r  = i - x * 224;
            gll16(gb + x * 14336 + c0 * 14 + r * 4, sb + ch * 256);
        }
    };
    auto stage_cm_rev = [&](const float* gb, float* sb) {
        #pragma unroll
        for (int j = 0; j < 7; ++j) {
            int ch = w0 + 7 * j;
            int i  = ch * 64 + lane;
            int x  = i / 224;
            int jj = (i - x * 224) << 2;
            int t  = c0 * 14 + jj;                // 16B group never straddles t%1024
            int hi = t >> 10, lo = t & 1023;
            int p  = 195 - x * 14 - hi;
            gll16(gb + p * N_C + lo, sb + ch * 256);
        }
    };

    float acc[28];

    auto acc_perm = [&](const float* sb, auto pf, bool first) {
        #pragma unroll
        for (int k = 0; k < 28; ++k) {
            int q = w0 * 28 + k;
            int p = pf(q);
            float v = sb[p * 64 + lane];
            if (first) acc[k] = v; else acc[k] += v;
        }
    };
    auto acc_cm = [&](const float* sb) {
        #pragma unroll
        for (int x = 0; x < 14; ++x) {
            float2 v = *(const float2*)(sb + x * 896 + lane * 14 + 2 * w0);
            acc[x]      += v.x;
            acc[14 + x] += v.y;
        }
    };

    // ---- pipelined phases ----
    stage_perm  (in0 + boff, bufA);
    stage_perm  (in1 + boff, bufB);
    stage_cm_fwd(in2 + boff, bufC);

    VM(14); BAR();
    acc_perm(bufA, [](int q){ return q; }, true);
    BAR(); stage_cm_rev(in3 + boff, bufA);

    VM(14); BAR();
    acc_perm(bufB, [](int q){ return 195 - q; }, false);
    BAR(); stage_perm(in4 + boff, bufB);

    VM(14); BAR();
    acc_cm(bufC);
    BAR(); stage_perm(in5 + boff, bufC);

    VM(14); BAR();
    acc_cm(bufA);
    BAR(); stage_perm(in6 + boff, bufA);

    VM(14); BAR();
    acc_perm(bufB, [](int q){ return (int)d_luts.p5[q]; }, false);
    BAR(); stage_perm(in7 + boff, bufB);

    VM(14); BAR();
    acc_perm(bufC, [](int q){ return (int)d_luts.p6[q]; }, false);
    BAR();

    VM(7); BAR();
    acc_perm(bufA, [](int q){ return (int)d_luts.p7[q]; }, false);

    VM(0); BAR();
    acc_perm(bufB, [](int q){ return (int)d_luts.p7[195 - q]; }, false);

    // ---- transpose via LDS (stride 65), coalesced store ----
    __syncthreads();                     // all reads of bufA/bufB done before overwrite
    float* tr = lds;                     // 196*65 = 12740 floats, fits in bufA+bufB
    #pragma unroll
    for (int k = 0; k < 28; ++k) {
        int q = w0 * 28 + k;
        tr[q * 65 + lane] = acc[k];
    }
    __syncthreads();
    float* ob = out + boff;
    #pragma unroll 4
    for (int i = tid; i < 64 * N_HW; i += 448) {
        int cg = i / N_HW;
        int q  = i - cg * N_HW;
        ob[(c0 + cg) * N_HW + q] = tr[q * 65 + cg];
    }
}

extern "C" void kernel_launch(void* const* d_in, const int* in_sizes, int n_in,
                              void* d_out, int out_size, void* d_ws, size_t ws_size,
                              hipStream_t stream) {
    dim3 grid(16, 64);   // x: channel tile (1024/64), y: batch
    dim3 block(448);     // 7 waves
    recon_kernel<<<grid, block, 0, stream>>>(
        (const float*)d_in[0], (const float*)d_in[1], (const float*)d_in[2],
        (const float*)d_in[3], (const float*)d_in[4], (const float*)d_in[5],
        (const float*)d_in[6], (const float*)d_in[7], (float*)d_out);
}